// Round 8
// baseline (41.304 us; speedup 1.0000x reference)
//
#include <hip/hip_runtime.h>
#include <stdint.h>

// PropNet cost-volume via bf16 MFMA — single fused kernel with a 2-deep
// counted-vmcnt DMA pipeline (T3/T4): double-buffered fp32 staging tile,
// raw s_barriers, vmcnt never drained to 0 in the main loop.
// N=2, C=256, H=W=96, max_distance=4 (window 9x9), num_class=124.
#define Nn 2
#define Cc 256
#define Hh 96
#define Ww 96
#define HW (Hh * Ww)
#define MD 4
#define NC 124
#define TH 4                    // dest tile rows
#define TWD 8                   // dest tile cols
#define NQ (TH * TWD)           // 32 dest pixels (MFMA M)
#define SH (TH + 2 * MD)        // 12 window rows
#define SWD (TWD + 2 * MD)      // 16 window cols
#define NS (SH * SWD)           // 192 src pixels (MFMA N)
#define BLK 256                 // 4 waves
#define NBW (Ww / TWD)          // 12
#define NBH (Hh / TH)           // 24
#define NBLK (Nn * NBH * NBW)   // 576 blocks (divisible by 8)
#define YROW 64                 // bytes per pixel row in a chunk (32 ch * 2B)
#define XOFF (NS * YROW)        // 12288: x region offset inside B buffer
#define BUFSZ (XOFF + NQ * YROW) // 14336 bytes
#define TBL (NQ * NC)           // 3968 table entries (15872B <= one F buffer)
#define FW (32 * NS)            // 6144 words: fp32 y staging per buffer
#define XFW (32 * NQ)           // 1024 words: fp32 x staging per buffer
#define FBUF (FW + XFW)         // 7168 words = 28672 B per buffer

typedef short short8 __attribute__((ext_vector_type(8)));
typedef float f32x4 __attribute__((ext_vector_type(4)));

// Monotone float -> uint mapping so unsigned min == float min.
__device__ __forceinline__ unsigned fmap(float f) {
    unsigned b = __float_as_uint(f);
    return (b & 0x80000000u) ? ~b : (b | 0x80000000u);
}
__device__ __forceinline__ float funmap(unsigned u) {
    unsigned b = (u & 0x80000000u) ? (u & 0x7fffffffu) : ~u;
    return __uint_as_float(b);
}
// XOR-swizzled byte offset of 16B ch-slot `slot` in pixel-row `row`.
// Used by BOTH the pack writes and the fragment reads -> always consistent.
__device__ __forceinline__ int swz(int row, int slot) {
    return row * YROW + ((slot ^ ((row >> 1) & 3)) << 4);
}

__global__ __launch_bounds__(BLK, 2) void propnet_fused(
    const float* __restrict__ x, const float* __restrict__ y,
    const int* __restrict__ labels, float* __restrict__ out)
{
    __shared__ __align__(16) float F2[2][FBUF];           // 2x28KB fp32 staging
    __shared__ __align__(16) unsigned char B[BUFSZ];      // bf16 MFMA operands
    __shared__ float y2s[NS];
    __shared__ float x2s[NQ];
    __shared__ int   labs[NS];
    unsigned* table = (unsigned*)&F2[0][0];  // aliased after the K-loop

    const int t = threadIdx.x;

    // XCD-aware bijective swizzle: contiguous 72-block chunk per XCD.
    const int orig = blockIdx.x;
    const int lin  = (orig & 7) * (NBLK / 8) + (orig >> 3);
    const int n    = lin / (NBH * NBW);
    const int rem  = lin - n * (NBH * NBW);
    const int h0   = (rem / NBW) * TH;
    const int w0   = (rem % NBW) * TWD;
    const size_t nb = (size_t)n * Cc * HW;

    if (t < NS) {
        const int sr = t >> 4, sc = t & 15;
        const int gh = h0 - MD + sr, gw = w0 - MD + sc;
        const bool ok = (gh >= 0) && (gh < Hh) && (gw >= 0) && (gw < Ww);
        labs[t] = ok ? labels[(size_t)n * HW + gh * Ww + gw] : -1;  // -1: excluded
        y2s[t]  = 0.f;
    }
    if (t < NQ) x2s[t] = 0.f;

    const int lane = t & 63;
    const int wid  = t >> 6;          // 0..3

    // ---- DMA descriptors: 28 insts/chunk, EXACTLY 7 per wave (uniform ->
    // counted vmcnt is valid). m = wid*7+k; m<24: y tasks (ch*48+g*4+sg,
    // 16B each, F linear); m>=24: x tasks (ch*8+seg). Window edge rows/segs
    // clamp in-range (garbage excluded via labs).
    const char* sp[7]; int ld[7];
#pragma unroll
    for (int k = 0; k < 7; ++k) {
        const int m = wid * 7 + k;
        if (m < 24) {
            const int task = m * 64 + lane;
            const int ch = task / 48;
            const int r  = task - ch * 48;
            const int g  = r >> 2;
            const int sg = r & 3;
            const int gh = min(max(h0 - MD + g, 0), Hh - 1);
            const int ws = min(max(w0 - MD + sg * 4, 0), Ww - 4);
            sp[k] = (const char*)(y + nb) + (size_t)(ch * HW + gh * Ww + ws) * 4;
            ld[k] = m * 1024;
        } else {
            const int u  = (m - 24) * 64 + lane;     // 0..255
            const int ch = u >> 3;
            const int seg = u & 7;                   // p = seg*4+idx == dest q
            sp[k] = (const char*)(x + nb) +
                    (size_t)(ch * HW + (h0 + (seg >> 1)) * Ww + w0 + (seg & 1) * 4) * 4;
            ld[k] = FW * 4 + (m - 24) * 1024;
        }
    }
    auto stage = [&](int b, int c) {
        const size_t coff = (size_t)(c * 32) * HW * 4;
        char* Fb = (char*)F2[b];
#pragma unroll
        for (int k = 0; k < 7; ++k)
            __builtin_amdgcn_global_load_lds(
                (const __attribute__((address_space(1))) unsigned int*)(sp[k] + coff),
                (__attribute__((address_space(3))) unsigned int*)(Fb + ld[k]),
                16, 0, 0);
    };

    // ---- pack descriptors: y 768 tasks (3/thread) + x 128 (t<128). ----
    int pco[3], pwb[3], ppix[3];
#pragma unroll
    for (int i = 0; i < 3; ++i) {
        const int task = t + 256 * i;
        const int pix  = task % NS;
        const int slot = task / NS;
        ppix[i] = pix;
        pwb[i]  = swz(pix, slot);
        pco[i]  = slot * 8 * NS + pix;     // stride NS words (2-way banks)
    }
    const bool xw = (t < 128);
    int xco = 0, xwb = 0, xpix = 0;
    if (xw) {
        xpix = t & 31;
        const int slot = t >> 5;
        xco = FW + slot * 8 * NQ + xpix;   // stride NQ words (2-way banks)
        xwb = XOFF + swz(xpix, slot);
    }
    float ysq[3] = {0.f, 0.f, 0.f};
    float xsq = 0.f;
    auto pack = [&](int b) {
        const float* Fb = F2[b];
#pragma unroll
        for (int i = 0; i < 3; ++i) {
            float v[8];
#pragma unroll
            for (int j = 0; j < 8; ++j) v[j] = Fb[pco[i] + j * NS];
            unsigned pk[4];
#pragma unroll
            for (int j = 0; j < 4; ++j) {
                ysq[i] = fmaf(v[2*j],   v[2*j],   ysq[i]);
                ysq[i] = fmaf(v[2*j+1], v[2*j+1], ysq[i]);
                pk[j] = (__float_as_uint(v[2*j]) >> 16) |
                        (__float_as_uint(v[2*j+1]) & 0xffff0000u);
            }
            *(uint4*)(B + pwb[i]) = make_uint4(pk[0], pk[1], pk[2], pk[3]);
        }
        if (xw) {
            float v[8];
#pragma unroll
            for (int j = 0; j < 8; ++j) v[j] = Fb[xco + j * NQ];
            unsigned pk[4];
#pragma unroll
            for (int j = 0; j < 4; ++j) {
                xsq = fmaf(v[2*j],   v[2*j],   xsq);
                xsq = fmaf(v[2*j+1], v[2*j+1], xsq);
                pk[j] = (__float_as_uint(v[2*j]) >> 16) |
                        (__float_as_uint(v[2*j+1]) & 0xffff0000u);
            }
            *(uint4*)(B + xwb) = make_uint4(pk[0], pk[1], pk[2], pk[3]);
        }
    };

    // ---- MFMA fragments ----
    const int l15 = lane & 15;
    const int lg  = lane >> 4;        // 8-ch k-slot
    int aoff[2], boff[3];
#pragma unroll
    for (int mf = 0; mf < 2; ++mf) aoff[mf] = XOFF + swz(mf * 16 + l15, lg);
#pragma unroll
    for (int nf = 0; nf < 3; ++nf) boff[nf] = swz(wid * 48 + nf * 16 + l15, lg);

    f32x4 acc[2][3];
#pragma unroll
    for (int mf = 0; mf < 2; ++mf)
#pragma unroll
        for (int nf = 0; nf < 3; ++nf)
            acc[mf][nf] = (f32x4){0.f, 0.f, 0.f, 0.f};

    auto compute = [&]() {
        short8 a[2], b[3];
#pragma unroll
        for (int mf = 0; mf < 2; ++mf) a[mf] = *(const short8*)(B + aoff[mf]);
#pragma unroll
        for (int nf = 0; nf < 3; ++nf) b[nf] = *(const short8*)(B + boff[nf]);
#pragma unroll
        for (int mf = 0; mf < 2; ++mf)
#pragma unroll
            for (int nf = 0; nf < 3; ++nf)
                acc[mf][nf] = __builtin_amdgcn_mfma_f32_16x16x32_bf16(
                    a[mf], b[nf], acc[mf][nf], 0, 0, 0);
    };

    // ---- pipeline. Loop invariant: only stage() issues VMEM inside the
    // loop (7 insts/wave/chunk); vmcnt(7) == "oldest chunk landed".
    __syncthreads();            // drain prologue loads -> vmcnt 0 everywhere
    stage(0, 0);
    stage(1, 1);                // 2 chunks (14 insts/wave) in flight
#pragma unroll
    for (int c = 0; c < 8; ++c) {
        if (c < 7) asm volatile("s_waitcnt vmcnt(7)" ::: "memory");
        else       asm volatile("s_waitcnt vmcnt(0)" ::: "memory");
        __builtin_amdgcn_sched_barrier(0);
        __builtin_amdgcn_s_barrier();          // join: F2[c&1] fully landed
        __builtin_amdgcn_sched_barrier(0);
        asm volatile("" ::: "memory");         // no LDS reads hoist above
        pack(c & 1);                           // F2[c&1] -> B (bf16, swizzled)
        asm volatile("s_waitcnt lgkmcnt(0)" ::: "memory");
        __builtin_amdgcn_sched_barrier(0);
        __builtin_amdgcn_s_barrier();          // join: B complete, F2[c&1] free
        __builtin_amdgcn_sched_barrier(0);
        asm volatile("" ::: "memory");
        if (c < 6) stage(c & 1, c + 2);        // refill freed buffer; flies over
        compute();                             // MFMA chunk c from B
    }

    // ---- norms reduce; init tables (F2 dead now) ----
#pragma unroll
    for (int i = 0; i < 3; ++i) atomicAdd(&y2s[ppix[i]], ysq[i]);
    if (xw) atomicAdd(&x2s[xpix], xsq);
    for (int i = t; i < TBL; i += BLK) table[i] = 0xBF800000u;  // fmap(1.0f)
    __syncthreads();

    // ---- epilogue: d -> sigmoid -> label-masked min ----
    // C layout: col(n) = l&15, row(m) = (l>>4)*4 + reg.
#pragma unroll
    for (int mf = 0; mf < 2; ++mf) {
#pragma unroll
        for (int nf = 0; nf < 3; ++nf) {
#pragma unroll
            for (int r = 0; r < 4; ++r) {
                const int q = mf * 16 + lg * 4 + r;       // dest pixel 0..31
                const int s = wid * 48 + nf * 16 + l15;   // src pixel 0..191
                const int qr = q >> 3, qc = q & 7;
                const int sr = s >> 4, sc = s & 15;
                const int di = sr - qr, dj = sc - qc;
                const int lab = labs[s];
                if (di >= 0 && di <= 2 * MD && dj >= 0 && dj <= 2 * MD &&
                    lab >= 0 && lab < NC) {
                    const float d  = x2s[q] + y2s[s] - 2.0f * acc[mf][nf][r];
                    const float sg = 1.0f / (1.0f + __expf(-d));
                    atomicMin(&table[q * NC + lab], fmap(fmaf(2.0f, sg, -1.0f)));
                }
            }
        }
    }
    __syncthreads();

    // ---- write out[n][class][h0+qr][w0+qc] ----
    const size_t ob = (size_t)n * NC * HW;
    for (int i = t; i < TBL; i += BLK) {
        const int g = i >> 5;        // class
        const int q = i & 31;        // dest pixel
        const int qr = q >> 3, qc = q & 7;
        out[ob + (size_t)g * HW + (size_t)(h0 + qr) * Ww + (w0 + qc)] =
            funmap(table[q * NC + g]);
    }
}

extern "C" void kernel_launch(void* const* d_in, const int* in_sizes, int n_in,
                              void* d_out, int out_size, void* d_ws, size_t ws_size,
                              hipStream_t stream) {
    const float* x      = (const float*)d_in[0];
    const float* y      = (const float*)d_in[1];
    const int*   labels = (const int*)d_in[2];
    float*       out    = (float*)d_out;
    (void)in_sizes; (void)n_in; (void)out_size; (void)d_ws; (void)ws_size;

    propnet_fused<<<dim3(NBLK), dim3(BLK), 0, stream>>>(x, y, labels, out);
}

// Round 9
// 32.156 us; speedup vs baseline: 1.2845x; 1.2845x over previous
//
#include <hip/hip_runtime.h>
#include <stdint.h>

// PropNet cost-volume via bf16 MFMA.
// Prep: streaming transpose of BOTH x and y to bf16 [n][cq][pix][8ch]
//   (1KB-contiguous reads AND writes; per-pixel norm partials in-thread,
//   no atomics/memset). Main (= round-3 verified kernel): pure
//   global_load_lds DMA of the transposed tensors, MFMA, fused epilogue.
// N=2, C=256, H=W=96, max_distance=4 (window 9x9), num_class=124.
#define Nn 2
#define Cc 256
#define Hh 96
#define Ww 96
#define HW (Hh * Ww)
#define MD 4
#define NC 124
#define TH 4                    // dest tile rows
#define TWD 8                   // dest tile cols
#define NQ (TH * TWD)           // 32 dest pixels (MFMA M)
#define SH (TH + 2 * MD)        // 12 window rows
#define SWD (TWD + 2 * MD)      // 16 window cols
#define NS (SH * SWD)           // 192 src pixels (MFMA N)
#define BLK 256                 // 4 waves
#define NBW (Ww / TWD)          // 12
#define NBH (Hh / TH)           // 24
#define NBLK (Nn * NBH * NBW)   // 576 blocks (divisible by 8)
#define YROW 64                 // bytes per pixel row in a chunk (32 ch * 2B)
#define XOFF (NS * YROW)        // 12288: x region offset inside B buffer
#define BUFSZ (XOFF + NQ * YROW) // 14336 bytes per buffer
#define TBL (NQ * NC)           // 3968 table entries (15872B <= 2*BUFSZ)
#define CQ 32                   // 8-channel groups in C=256

// prep geometry: block = 256 px x 64 ch x one tensor
#define PPX 256
#define NSTR (HW / PPX)         // 36 strips
#define PBLK (2 * Nn * 4 * NSTR)  // 576 blocks

// workspace layout (bytes)
#define TEN_BYTES ((size_t)Nn * CQ * HW * 16)   // 9.44 MB per tensor
#define XT_OFF    TEN_BYTES
#define PART_OFF  (TEN_BYTES * 2)               // parts[ten][g4][n][HW] f32

typedef short short8 __attribute__((ext_vector_type(8)));
typedef float f32x4 __attribute__((ext_vector_type(4)));

// Monotone float -> uint mapping so unsigned min == float min.
__device__ __forceinline__ unsigned fmap(float f) {
    unsigned b = __float_as_uint(f);
    return (b & 0x80000000u) ? ~b : (b | 0x80000000u);
}
__device__ __forceinline__ float funmap(unsigned u) {
    unsigned b = (u & 0x80000000u) ? (u & 0x7fffffffu) : ~u;
    return __uint_as_float(b);
}
// XOR-swizzled byte offset of 16B ch-slot `slot` in pixel-row `row`.
__device__ __forceinline__ int swz(int row, int slot) {
    return row * YROW + ((slot ^ ((row >> 1) & 3)) << 4);
}

// ---------------- prep: fp32 NCHW -> bf16 [n][cq][pix][8], norm partials ----
__global__ __launch_bounds__(256) void prep_t(
    const float* __restrict__ x, const float* __restrict__ y,
    uint4* __restrict__ yT, uint4* __restrict__ xT, float* __restrict__ parts)
{
    __shared__ float tile[64 * PPX];   // 64 KB fp32 staging [chL][px]
    const int t = threadIdx.x;
    const int bid = blockIdx.x;
    const int strip = bid % NSTR;
    const int rest  = bid / NSTR;      // 0..15
    const int g4  = rest & 3;          // channel quarter (64 ch)
    const int n   = (rest >> 2) & 1;
    const int ten = rest >> 3;         // 0 = y, 1 = x
    const int pix0 = strip * PPX;
    const float* src = (ten ? x : y) + ((size_t)n * Cc + g4 * 64) * HW + pix0;
    uint4* dstT = (ten ? xT : yT) + (size_t)n * CQ * HW;

    const int wid = t >> 6, lane = t & 63;
    // 16 loads/thread; each wave-inst = one channel row-segment = 1KB contiguous.
#pragma unroll
    for (int k = 0; k < 16; ++k) {
        const int m = wid * 16 + k;    // local channel 0..63
        const float4 v = *(const float4*)(src + (size_t)m * HW + lane * 4);
        *(float4*)&tile[m * PPX + lane * 4] = v;
    }
    __syncthreads();

    // pack: thread owns px = t for all 8 local cq slices -> norms in-thread.
    float sq = 0.f;
#pragma unroll
    for (int k = 0; k < 8; ++k) {
        float v[8];
#pragma unroll
        for (int j = 0; j < 8; ++j) v[j] = tile[(k * 8 + j) * PPX + t];
        unsigned pk[4];
#pragma unroll
        for (int j = 0; j < 4; ++j) {
            sq = fmaf(v[2*j],   v[2*j],   sq);
            sq = fmaf(v[2*j+1], v[2*j+1], sq);
            pk[j] = (__float_as_uint(v[2*j]) >> 16) |
                    (__float_as_uint(v[2*j+1]) & 0xffff0000u);
        }
        dstT[(size_t)(g4 * 8 + k) * HW + pix0 + t] =
            make_uint4(pk[0], pk[1], pk[2], pk[3]);   // 1KB contiguous runs
    }
    parts[((size_t)(ten * 4 + g4) * Nn + n) * HW + pix0 + t] = sq;
}

// ---------------- main kernel (round-3 verified, partial-sum prologue) -----
__global__ __launch_bounds__(BLK) void propnet_mfma(
    const uint4* __restrict__ yT, const uint4* __restrict__ xT,
    const float* __restrict__ parts, const int* __restrict__ labels,
    float* __restrict__ out)
{
    __shared__ __align__(16) unsigned char sbuf[2][BUFSZ];  // double-buffered staging
    __shared__ float y2s[NS];
    __shared__ float x2s[NQ];
    __shared__ int   labs[NS];
    unsigned* table = (unsigned*)&sbuf[0][0];  // aliased after the K-loop

    const int t = threadIdx.x;

    // XCD-aware bijective swizzle: contiguous 72-block chunk per XCD.
    const int orig = blockIdx.x;
    const int lin  = (orig & 7) * (NBLK / 8) + (orig >> 3);
    const int n    = lin / (NBH * NBW);
    const int rem  = lin - n * (NBH * NBW);
    const int h0   = (rem / NBW) * TH;
    const int w0   = (rem % NBW) * TWD;

    const float* ypart = parts;                       // [4][Nn][HW]
    const float* xpart = parts + (size_t)4 * Nn * HW;

    if (t < NS) {
        const int sr = t >> 4, sc = t & 15;
        const int gh = h0 - MD + sr, gw = w0 - MD + sc;
        const bool ok = (gh >= 0) && (gh < Hh) && (gw >= 0) && (gw < Ww);
        labs[t] = ok ? labels[(size_t)n * HW + gh * Ww + gw] : -1;  // -1: excluded
        float s = 0.f;
        if (ok) {
            const size_t idx = (size_t)n * HW + gh * Ww + gw;
#pragma unroll
            for (int g = 0; g < 4; ++g) s += ypart[(size_t)g * Nn * HW + idx];
        }
        y2s[t] = s;
    }
    if (t < NQ) {
        const size_t idx = (size_t)n * HW + (size_t)(h0 + (t >> 3)) * Ww + (w0 + (t & 7));
        float s = 0.f;
#pragma unroll
        for (int g = 0; g < 4; ++g) s += xpart[(size_t)g * Nn * HW + idx];
        x2s[t] = s;
    }

    const int lane = t & 63;
    const int wid  = t >> 6;

    // ---- y DMA: 3 insts/wave/chunk; linear LDS dest, swizzle realized by
    // permuting the per-lane GLOBAL source (rule #21).
    size_t ysrc[3]; int yl[3];
    {
        const int sc4 = lane >> 2;                 // pixel col within 16-group
        const int pos = lane & 3;                  // 16B position in pixel row
        const int cqw = pos ^ ((sc4 >> 1) & 3);    // ch-slot stored at this pos
#pragma unroll
        for (int i = 0; i < 3; ++i) {
            const int g  = wid * 3 + i;            // window row 0..11
            const int gh = min(max(h0 - MD + g, 0), Hh - 1);   // clamp; excluded by labs
            const int gw = min(max(w0 - MD + sc4, 0), Ww - 1);
            ysrc[i] = (size_t)cqw * HW + (size_t)gh * Ww + gw;
            yl[i]   = g * 1024;                    // 16 pixels * 64B
        }
    }
    // ---- x DMA: 1 inst each on waves 0,1 (2KB region).
    const bool hasx = (wid < 2);
    size_t xsrc = 0; int xl = 0;
    if (hasx) {
        const int q   = wid * 16 + (lane >> 2);    // dest pixel 0..31
        const int pos = lane & 3;
        const int s   = pos ^ ((q >> 1) & 3);      // slot stored at this pos
        xsrc = (size_t)s * HW + (size_t)(h0 + (q >> 3)) * Ww + (w0 + (q & 7));
        xl   = XOFF + wid * 1024;
    }
    const uint4* yTn = yT + (size_t)n * CQ * HW;
    const uint4* xTn = xT + (size_t)n * CQ * HW;
    auto stage = [&](int b, int c) {
        const uint4* yb = yTn + (size_t)(c * 4) * HW;
#pragma unroll
        for (int i = 0; i < 3; ++i)
            __builtin_amdgcn_global_load_lds(
                (const __attribute__((address_space(1))) unsigned int*)(yb + ysrc[i]),
                (__attribute__((address_space(3))) unsigned int*)(sbuf[b] + yl[i]),
                16, 0, 0);
        if (hasx)
            __builtin_amdgcn_global_load_lds(
                (const __attribute__((address_space(1))) unsigned int*)
                    (xTn + (size_t)(c * 4) * HW + xsrc),
                (__attribute__((address_space(3))) unsigned int*)(sbuf[b] + xl),
                16, 0, 0);
    };

    // ---- MFMA fragments ----
    const int l15 = lane & 15;
    const int lg  = lane >> 4;        // 8-ch k-slot
    int aoff[2], boff[3];
#pragma unroll
    for (int mf = 0; mf < 2; ++mf) aoff[mf] = XOFF + swz(mf * 16 + l15, lg);
#pragma unroll
    for (int nf = 0; nf < 3; ++nf) boff[nf] = swz(wid * 48 + nf * 16 + l15, lg);

    f32x4 acc[2][3];
#pragma unroll
    for (int mf = 0; mf < 2; ++mf)
#pragma unroll
        for (int nf = 0; nf < 3; ++nf)
            acc[mf][nf] = (f32x4){0.f, 0.f, 0.f, 0.f};

    auto compute = [&](const unsigned char* bb) {
        short8 a[2], b[3];
#pragma unroll
        for (int mf = 0; mf < 2; ++mf) a[mf] = *(const short8*)(bb + aoff[mf]);
#pragma unroll
        for (int nf = 0; nf < 3; ++nf) b[nf] = *(const short8*)(bb + boff[nf]);
#pragma unroll
        for (int mf = 0; mf < 2; ++mf)
#pragma unroll
            for (int nf = 0; nf < 3; ++nf)
                acc[mf][nf] = __builtin_amdgcn_mfma_f32_16x16x32_bf16(
                    a[mf], b[nf], acc[mf][nf], 0, 0, 0);
    };

    // ---- K-loop: 8 chunks of 32 ch, double-buffered, pure DMA staging ----
    stage(0, 0);
    __syncthreads();
    for (int c = 0; c < 8; ++c) {
        const int b = c & 1;
        if (c < 7) stage(b ^ 1, c + 1);   // next-chunk DMA flies over MFMAs
        compute(sbuf[b]);
        __syncthreads();                   // drains vmcnt -> next buf ready
    }

    // ---- init tables (staging buffers dead now) ----
    for (int i = t; i < TBL; i += BLK) table[i] = 0xBF800000u;  // fmap(1.0f)
    __syncthreads();

    // ---- epilogue: d -> sigmoid -> label-masked min ----
    // C layout: col(n) = l&15, row(m) = (l>>4)*4 + reg.
#pragma unroll
    for (int mf = 0; mf < 2; ++mf) {
#pragma unroll
        for (int nf = 0; nf < 3; ++nf) {
#pragma unroll
            for (int r = 0; r < 4; ++r) {
                const int q = mf * 16 + lg * 4 + r;       // dest pixel 0..31
                const int s = wid * 48 + nf * 16 + l15;   // src pixel 0..191
                const int qr = q >> 3, qc = q & 7;
                const int sr = s >> 4, sc = s & 15;
                const int di = sr - qr, dj = sc - qc;
                const int lab = labs[s];
                if (di >= 0 && di <= 2 * MD && dj >= 0 && dj <= 2 * MD &&
                    lab >= 0 && lab < NC) {
                    const float d  = x2s[q] + y2s[s] - 2.0f * acc[mf][nf][r];
                    const float sg = 1.0f / (1.0f + __expf(-d));
                    atomicMin(&table[q * NC + lab], fmap(fmaf(2.0f, sg, -1.0f)));
                }
            }
        }
    }
    __syncthreads();

    // ---- write out[n][class][h0+qr][w0+qc] ----
    const size_t ob = (size_t)n * NC * HW;
    for (int i = t; i < TBL; i += BLK) {
        const int g = i >> 5;        // class
        const int q = i & 31;        // dest pixel
        const int qr = q >> 3, qc = q & 7;
        out[ob + (size_t)g * HW + (size_t)(h0 + qr) * Ww + (w0 + qc)] =
            funmap(table[q * NC + g]);
    }
}

extern "C" void kernel_launch(void* const* d_in, const int* in_sizes, int n_in,
                              void* d_out, int out_size, void* d_ws, size_t ws_size,
                              hipStream_t stream) {
    const float* x      = (const float*)d_in[0];
    const float* y      = (const float*)d_in[1];
    const int*   labels = (const int*)d_in[2];
    float*       out    = (float*)d_out;
    uint4* yT    = (uint4*)d_ws;
    uint4* xT    = (uint4*)((char*)d_ws + XT_OFF);
    float* parts = (float*)((char*)d_ws + PART_OFF);
    (void)in_sizes; (void)n_in; (void)out_size; (void)ws_size;

    prep_t<<<dim3(PBLK), dim3(256), 0, stream>>>(x, y, yT, xT, parts);
    propnet_mfma<<<dim3(NBLK), dim3(BLK), 0, stream>>>(yT, xT, parts, labels, out);
}